// Round 4
// baseline (303.135 us; speedup 1.0000x reference)
//
#include <hip/hip_runtime.h>
#include <cmath>

#define NB   2048
#define ND   512
#define NL   8
#define NLAB 128
#define MAXM 64
#define TOPK_ 5
#define NTH  256
#define MAXSLOT 9            // ceil(64*65/2 / 256)
#define GSTRIDE (MAXM*MAXM)  // 4096 floats per (label,layer) gram

// ---------------------------------------------------------------------------
// Fused bucket + raw Gram per (label, layer). Each block rebuilds its label's
// member list (index-ascending) from labels[] (8 KB, L2), then computes the
// un-normalized dot-product Gram incl. diag. Block (0,0) zeroes the ticket.
// ---------------------------------------------------------------------------
__global__ __launch_bounds__(NTH) void k_gram(
    const float* __restrict__ feats, const int* __restrict__ labels,
    float* __restrict__ G, unsigned* __restrict__ ticket)
{
    __shared__ int cnts[NTH];
    __shared__ int g_s[MAXM];
    __shared__ float Xt[MAXM][132];   // 132%4==0 -> aligned float4 rows
    int c = blockIdx.x, l = blockIdx.y, tid = threadIdx.x;
    if (c == 0 && l == 0 && tid == 0) *ticket = 0u;

    // in-block bucket (deterministic, index-ascending)
    int my[8]; int n = 0; int base_i = tid * 8;
    for (int t = 0; t < 8; ++t) {
        int i = base_i + t;
        if (labels[i] == c) my[n++] = i;
    }
    cnts[tid] = n;
    __syncthreads();
    for (int off = 1; off < NTH; off <<= 1) {
        int v = (tid >= off) ? cnts[tid - off] : 0;
        __syncthreads();
        cnts[tid] += v;
        __syncthreads();
    }
    int excl = cnts[tid] - n;
    int m = cnts[NTH - 1]; if (m > MAXM) m = MAXM;
    for (int t = 0; t < n; ++t) {
        int slot = excl + t;
        if (slot < MAXM) g_s[slot] = my[t];
    }
    __syncthreads();
    if (m == 0) return;

    const float* X = feats + (size_t)l * NB * ND;
    const int P = m * (m + 1) / 2;    // triangular incl. diag
    float acc0[MAXSLOT], acc1[MAXSLOT];
    short is_[MAXSLOT], js_[MAXSLOT];
    int ns = 0;
    for (int p = tid; p < P; p += NTH) {
        int i = (int)((sqrtf(8.0f * (float)p + 1.0f) - 1.0f) * 0.5f);
        while (((i + 1) * (i + 2)) / 2 <= p) ++i;
        while ((i * (i + 1)) / 2 > p) --i;
        is_[ns] = (short)i;
        js_[ns] = (short)(p - (i * (i + 1)) / 2);
        acc0[ns] = 0.0f; acc1[ns] = 0.0f;
        ++ns;
    }
    for (int kc = 0; kc < ND; kc += 128) {
        if (kc) __syncthreads();      // previous chunk's readers done
        for (int idx = tid; idx < (m << 5); idx += NTH) {
            int i = idx >> 5, k4 = idx & 31;
            float4 v = *(const float4*)(X + ((size_t)g_s[i] << 9) + kc + (k4 << 2));
            *(float4*)&Xt[i][k4 << 2] = v;
        }
        __syncthreads();
        for (int s = 0; s < ns; ++s) {
            int i = is_[s], j = js_[s];
            float a0 = acc0[s], a1 = acc1[s];
            #pragma unroll
            for (int k4 = 0; k4 < 32; ++k4) {
                float4 a = *(const float4*)&Xt[i][k4 << 2];
                float4 b = *(const float4*)&Xt[j][k4 << 2];
                a0 = fmaf(a.x, b.x, a0); a1 = fmaf(a.y, b.y, a1);
                a0 = fmaf(a.z, b.z, a0); a1 = fmaf(a.w, b.w, a1);
            }
            acc0[s] = a0; acc1[s] = a1;
        }
    }
    float* Gc = G + ((size_t)l * NLAB + c) * GSTRIDE;
    for (int s = 0; s < ns; ++s) {
        int i = is_[s], j = js_[s];
        float v = acc0[s] + acc1[s];
        Gc[i * MAXM + j] = v;
        Gc[j * MAXM + i] = v;
    }
}

// ---------------------------------------------------------------------------
// One block per label: phase1 (layer-7 knn -> insub), decide l=0..7
// (Mbits/ema in LDS), pairs p=0..6 -> private partial slot, then
// threadfence+ticket; last block reduces partials and writes out.
// ---------------------------------------------------------------------------
__global__ __launch_bounds__(NTH) void k_rest(
    const float* __restrict__ G, const int* __restrict__ labels,
    float* __restrict__ partial,   // [NL-1][NLAB][4]
    unsigned* __restrict__ ticket, float* __restrict__ out)
{
    __shared__ float Gs[64][65];
    __shared__ float rinv8[NL][64];
    __shared__ unsigned long long Mb[NL][64];
    __shared__ float es8[NL][64];
    __shared__ unsigned long long tops_s[64];
    __shared__ unsigned char keep_s[64];
    __shared__ int cnts[NTH];
    __shared__ unsigned long long insub_sh;
    __shared__ float red[12];
    __shared__ unsigned done_s;
    int c = blockIdx.x, tid = threadIdx.x;

    // count members of label c
    int n = 0; int base_i = tid * 8;
    for (int t = 0; t < 8; ++t) if (labels[base_i + t] == c) ++n;
    cnts[tid] = n;
    __syncthreads();
    for (int off = NTH / 2; off > 0; off >>= 1) {
        if (tid < off) cnts[tid] += cnts[tid + off];
        __syncthreads();
    }
    int m = cnts[0]; if (m > MAXM) m = MAXM;

    if (m > 0) {
        // ---------- phase 1: layer-7 full-group knn ----------
        const float* Gc7 = G + ((size_t)7 * NLAB + c) * GSTRIDE;
        if (tid < m) rinv8[7][tid] = 1.0f / fmaxf(sqrtf(Gc7[tid * MAXM + tid]), 1e-8f);
        __syncthreads();
        for (int idx = tid; idx < (m << 6); idx += NTH) {
            int i = idx >> 6, j = idx & 63;
            if (j < m) {
                float v = Gc7[idx] * rinv8[7][i] * rinv8[7][j];
                Gs[i][j] = fminf(fmaxf(v, -1.0f), 1.0f);  // jax f32 clip == +-1.0f
            }
        }
        __syncthreads();
        {
            unsigned long long tops = 0ull; bool keep = false;
            if (tid < m) {
                int cand = 0;
                for (int j = 0; j < m; ++j)
                    if (j != tid && Gs[tid][j] > 0.0f) ++cand;
                keep = (cand >= TOPK_);
                if (keep) {
                    for (int r = 0; r < TOPK_; ++r) {
                        float bv = 0.0f; int bj = -1;
                        for (int j = 0; j < m; ++j) {
                            if (j == tid || ((tops >> j) & 1ull)) continue;
                            float v = Gs[tid][j];
                            if (v > 0.0f && v > bv) { bv = v; bj = j; }  // ties -> lowest idx
                        }
                        if (bj >= 0) tops |= (1ull << bj);
                    }
                }
                keep_s[tid] = keep ? 1 : 0; tops_s[tid] = tops;
            }
            __syncthreads();
            unsigned long long Mrow = 0ull;
            if (tid < m && keep) {
                for (int j = 0; j < m; ++j) {
                    if (j == tid || !keep_s[j]) continue;
                    if (((tops >> j) & 1ull) || ((tops_s[j] >> tid) & 1ull)) Mrow |= (1ull << j);
                }
            }
            if (tid < 64) {
                unsigned long long b = __ballot(Mrow != 0ull);
                if (tid == 0) insub_sh = b;
            }
            __syncthreads();
        }
        unsigned long long sub = insub_sh;

        // ---------- decide for each layer ----------
        for (int l = 0; l < NL; ++l) {
            const float* Gc = G + ((size_t)l * NLAB + c) * GSTRIDE;
            if (tid < m) rinv8[l][tid] = 1.0f / fmaxf(sqrtf(Gc[tid * MAXM + tid]), 1e-8f);
            __syncthreads();
            for (int idx = tid; idx < (m << 6); idx += NTH) {
                int i = idx >> 6, j = idx & 63;
                if (j < m) {
                    float v = Gc[idx] * rinv8[l][i] * rinv8[l][j];
                    Gs[i][j] = fminf(fmaxf(v, -1.0f), 1.0f);
                }
            }
            __syncthreads();
            unsigned long long tops = 0ull; bool keep = false; bool act = false;
            if (tid < m) {
                act = (sub >> tid) & 1ull;
                int cand = 0;
                if (act) {
                    for (int j = 0; j < m; ++j)
                        if (j != tid && ((sub >> j) & 1ull) && Gs[tid][j] > 0.0f) ++cand;
                }
                keep = act && (cand >= TOPK_);
                if (keep) {
                    for (int r = 0; r < TOPK_; ++r) {
                        float bv = 0.0f; int bj = -1;
                        for (int j = 0; j < m; ++j) {
                            if (j == tid || !((sub >> j) & 1ull) || ((tops >> j) & 1ull)) continue;
                            float v = Gs[tid][j];
                            if (v > 0.0f && v > bv) { bv = v; bj = j; }
                        }
                        if (bj >= 0) tops |= (1ull << bj);
                    }
                }
                keep_s[tid] = keep ? 1 : 0; tops_s[tid] = tops;
            }
            __syncthreads();
            if (tid < m) {
                unsigned long long Mrow = 0ull;
                if (keep) {
                    for (int j = 0; j < m; ++j) {
                        if (j == tid || !keep_s[j]) continue;
                        if (((tops >> j) & 1ull) || ((tops_s[j] >> tid) & 1ull)) Mrow |= (1ull << j);
                    }
                }
                Mb[l][tid] = Mrow;
                float emaval = 0.0f;
                if (act) {
                    float rs = 0.0f; int dg = 0;
                    for (int j = 0; j < m; ++j) {
                        if ((sub >> j) & 1ull) {        // includes j == tid (diag ~ 1.0)
                            float v = Gs[tid][j];
                            if (v > 0.0f) { rs += v; ++dg; }
                        }
                    }
                    float deg = (float)(dg > 0 ? dg : 1);
                    float score = 1.0f / (1.0f + expf(-rs / deg));
                    emaval = 0.45f + 0.1f * score;      // MOM*0.5 + (1-MOM)*score
                }
                es8[l][tid] = emaval;
            }
            __syncthreads();   // Gs reads done before next layer overwrites
        }

        // ---------- pairs p = 0..6 ----------
        for (int p = 0; p < NL - 1; ++p) {
            const float* G0 = G + ((size_t)p       * NLAB + c) * GSTRIDE;
            const float* G1 = G + ((size_t)(p + 1) * NLAB + c) * GSTRIDE;
            float fn = 0.0f, fd = 0.0f, fc = 0.0f;
            for (int idx = tid; idx < (m << 6); idx += NTH) {
                int i = idx >> 6, j = idx & 63;
                if (j >= m) continue;
                bool b0 = (Mb[p][i] >> j) & 1ull;
                bool b1 = (Mb[p + 1][i] >> j) & 1ull;
                if (b0 | b1) {
                    float v0 = b0 ? fminf(fmaxf(G0[idx] * rinv8[p][i] * rinv8[p][j], -1.0f), 1.0f) : 0.0f;
                    float v1 = b1 ? fminf(fmaxf(G1[idx] * rinv8[p + 1][i] * rinv8[p + 1][j], -1.0f), 1.0f) : 0.0f;
                    float w = es8[p][i] * es8[p][j];     // W from shallow layer p
                    float d = v1 - v0;
                    fn = fmaf(d * d, w, fn);
                    fd += w;
                    fc += 1.0f;
                }
            }
            for (int off = 32; off > 0; off >>= 1) {
                fn += __shfl_down(fn, off);
                fd += __shfl_down(fd, off);
                fc += __shfl_down(fc, off);
            }
            int w = tid >> 6;
            if ((tid & 63) == 0) { red[w * 3] = fn; red[w * 3 + 1] = fd; red[w * 3 + 2] = fc; }
            __syncthreads();
            if (tid == 0) {
                float* dst = partial + ((size_t)p * NLAB + c) * 4;
                dst[0] = red[0] + red[3] + red[6] + red[9];
                dst[1] = red[1] + red[4] + red[7] + red[10];
                dst[2] = red[2] + red[5] + red[8] + red[11];
            }
            __syncthreads();   // red reused next p
        }
    } else {
        // m == 0: partials must still be defined (ws is poisoned)
        if (tid < NL - 1) {
            float* dst = partial + ((size_t)tid * NLAB + c) * 4;
            dst[0] = 0.0f; dst[1] = 0.0f; dst[2] = 0.0f;
        }
        __syncthreads();
    }

    // ---------- ticket: last block does the final reduction ----------
    __threadfence();                    // make this block's partials visible
    __syncthreads();
    if (tid == 0) done_s = atomicAdd(ticket, 1u);
    __syncthreads();
    if (done_s == NLAB - 1) {
        __threadfence();                // see all other blocks' partials
        if (tid < 64) {
            float total = 0.0f;
            for (int p = 0; p < NL - 1; ++p) {
                float nn = 0.0f, dd = 0.0f, cc = 0.0f;
                for (int cc_i = tid; cc_i < NLAB; cc_i += 64) {
                    const float* src = partial + ((size_t)p * NLAB + cc_i) * 4;
                    nn += src[0]; dd += src[1]; cc += src[2];
                }
                for (int off = 32; off > 0; off >>= 1) {
                    nn += __shfl_down(nn, off);
                    dd += __shfl_down(dd, off);
                    cc += __shfl_down(cc, off);
                }
                if (tid == 0 && cc > 0.0f) total += nn / fmaxf(dd, 1e-8f);
            }
            if (tid == 0) out[0] = 16.0f * total / 7.0f;  // LAMBDA * sum / (L-1)
        }
    }
}

extern "C" void kernel_launch(void* const* d_in, const int* in_sizes, int n_in,
                              void* d_out, int out_size, void* d_ws, size_t ws_size,
                              hipStream_t stream) {
    const float* feats  = (const float*)d_in[0];
    const int*   labels = (const int*)d_in[1];
    // (sample_ids unused by the reference)
    char* w = (char*)d_ws;
    float*    G       = (float*)(w);                                  // 16,777,216 B
    float*    partial = (float*)(w + (size_t)NL * NLAB * GSTRIDE * 4);// 14,336 B
    unsigned* ticket  = (unsigned*)(w + (size_t)NL * NLAB * GSTRIDE * 4 + 14336);
    float*    out     = (float*)d_out;

    k_gram<<<dim3(NLAB, NL), NTH, 0, stream>>>(feats, labels, G, ticket);
    k_rest<<<NLAB, NTH, 0, stream>>>(G, labels, partial, ticket, out);
}

// Round 5
// 183.381 us; speedup vs baseline: 1.6530x; 1.6530x over previous
//
#include <hip/hip_runtime.h>
#include <cmath>

#define NB   2048
#define ND   512
#define NL   8
#define NLAB 128
#define MAXM 64
#define TOPK_ 5
#define NTH  256
#define MAXSLOT 9            // ceil(64*65/2 / 256)
#define GSTRIDE (MAXM*MAXM)  // 4096 floats per (label,layer) gram

// ---------------------------------------------------------------------------
// Fused bucket + raw Gram per (label, layer). Each block rebuilds its label's
// member list (index-ascending) from labels[] (8 KB, L2), computes the
// un-normalized dot Gram incl. diag. l==0 blocks also publish cnt[c];
// block (0,0) zeroes the ticket for k_pairs.
// ---------------------------------------------------------------------------
__global__ __launch_bounds__(NTH) void k_gram(
    const float* __restrict__ feats, const int* __restrict__ labels,
    float* __restrict__ G, int* __restrict__ cnt, unsigned* __restrict__ ticket)
{
    __shared__ int cnts[NTH];
    __shared__ int g_s[MAXM];
    __shared__ float Xt[MAXM][132];   // 132%4==0 -> aligned float4 rows
    int c = blockIdx.x, l = blockIdx.y, tid = threadIdx.x;
    if (c == 0 && l == 0 && tid == 0) *ticket = 0u;

    // in-block bucket (deterministic, index-ascending)
    int my[8]; int n = 0; int base_i = tid * 8;
    for (int t = 0; t < 8; ++t) {
        int i = base_i + t;
        if (labels[i] == c) my[n++] = i;
    }
    cnts[tid] = n;
    __syncthreads();
    for (int off = 1; off < NTH; off <<= 1) {
        int v = (tid >= off) ? cnts[tid - off] : 0;
        __syncthreads();
        cnts[tid] += v;
        __syncthreads();
    }
    int excl = cnts[tid] - n;
    int m = cnts[NTH - 1]; if (m > MAXM) m = MAXM;
    for (int t = 0; t < n; ++t) {
        int slot = excl + t;
        if (slot < MAXM) g_s[slot] = my[t];
    }
    if (l == 0 && tid == 0) cnt[c] = m;
    __syncthreads();
    if (m == 0) return;

    const float* X = feats + (size_t)l * NB * ND;
    const int P = m * (m + 1) / 2;    // triangular incl. diag
    float acc0[MAXSLOT], acc1[MAXSLOT];
    short is_[MAXSLOT], js_[MAXSLOT];
    int ns = 0;
    for (int p = tid; p < P; p += NTH) {
        int i = (int)((sqrtf(8.0f * (float)p + 1.0f) - 1.0f) * 0.5f);
        while (((i + 1) * (i + 2)) / 2 <= p) ++i;
        while ((i * (i + 1)) / 2 > p) --i;
        is_[ns] = (short)i;
        js_[ns] = (short)(p - (i * (i + 1)) / 2);
        acc0[ns] = 0.0f; acc1[ns] = 0.0f;
        ++ns;
    }
    for (int kc = 0; kc < ND; kc += 128) {
        if (kc) __syncthreads();      // previous chunk's readers done
        for (int idx = tid; idx < (m << 5); idx += NTH) {
            int i = idx >> 5, k4 = idx & 31;
            float4 v = *(const float4*)(X + ((size_t)g_s[i] << 9) + kc + (k4 << 2));
            *(float4*)&Xt[i][k4 << 2] = v;
        }
        __syncthreads();
        for (int s = 0; s < ns; ++s) {
            int i = is_[s], j = js_[s];
            float a0 = acc0[s], a1 = acc1[s];
            #pragma unroll
            for (int k4 = 0; k4 < 32; ++k4) {
                float4 a = *(const float4*)&Xt[i][k4 << 2];
                float4 b = *(const float4*)&Xt[j][k4 << 2];
                a0 = fmaf(a.x, b.x, a0); a1 = fmaf(a.y, b.y, a1);
                a0 = fmaf(a.z, b.z, a0); a1 = fmaf(a.w, b.w, a1);
            }
            acc0[s] = a0; acc1[s] = a1;
        }
    }
    float* Gc = G + ((size_t)l * NLAB + c) * GSTRIDE;
    for (int s = 0; s < ns; ++s) {
        int i = is_[s], j = js_[s];
        float v = acc0[s] + acc1[s];
        Gc[i * MAXM + j] = v;
        Gc[j * MAXM + i] = v;
    }
}

// Load normalized+clipped tile (full 64x64, sentinel -2.0f outside m x m).
__device__ __forceinline__ void load_tile(
    const float* __restrict__ Gc, int m, int tid, float (*Gs)[65], float* rinv)
{
    if (tid < 64) rinv[tid] = (tid < m) ? 1.0f / fmaxf(sqrtf(Gc[tid * MAXM + tid]), 1e-8f) : 0.0f;
    __syncthreads();
    for (int idx = tid; idx < 4096; idx += NTH) {
        int i = idx >> 6, j = idx & 63;
        float raw = Gc[idx];                       // may be poison outside m x m
        float v = fminf(fmaxf(raw * rinv[i] * rinv[j], -1.0f), 1.0f);
        Gs[i][j] = (i < m && j < m) ? v : -2.0f;   // sentinel: fails every >0 test
    }
    __syncthreads();
}

// ---------------------------------------------------------------------------
// Per (label, layer): redundant phase-1 (layer-7 knn -> insub, block-local),
// then subset-restricted knn for layer l -> Mbits + ema.
// Top-k = single-pass 5-reg insertion (ascending j, strict > => ties->lowest
// index: identical selection to the verified iterative-max code).
// ---------------------------------------------------------------------------
__global__ __launch_bounds__(NTH) void k_decide(
    const float* __restrict__ G, const int* __restrict__ cnt,
    unsigned long long* __restrict__ Mbits, float* __restrict__ ema)
{
    __shared__ float Gs[64][65];
    __shared__ float rinv[64];
    __shared__ unsigned long long tops_s[64];
    __shared__ unsigned char keep_s[64];
    __shared__ unsigned long long insub_sh;
    int c = blockIdx.x, l = blockIdx.y, tid = threadIdx.x;
    int m = cnt[c]; if (m > MAXM) m = MAXM;
    if (m == 0) return;

    // ---------- phase 1 on layer-7 gram ----------
    const float* Gc7 = G + ((size_t)7 * NLAB + c) * GSTRIDE;
    load_tile(Gc7, m, tid, Gs, rinv);
    if (tid < 64) { keep_s[tid] = 0; tops_s[tid] = 0ull; }
    __syncthreads();
    {
        unsigned long long tops = 0ull; bool keep = false;
        if (tid < m) {
            float v0=-1.f,v1=-1.f,v2=-1.f,v3=-1.f,v4=-1.f;
            int i0=0,i1=0,i2=0,i3=0,i4=0, cand=0;
            #pragma unroll 8
            for (int j = 0; j < 64; ++j) {
                float v = Gs[tid][j];
                if (v > 0.0f && j != tid) {
                    ++cand;
                    if      (v > v0) { v4=v3;i4=i3; v3=v2;i3=i2; v2=v1;i2=i1; v1=v0;i1=i0; v0=v;i0=j; }
                    else if (v > v1) { v4=v3;i4=i3; v3=v2;i3=i2; v2=v1;i2=i1; v1=v;i1=j; }
                    else if (v > v2) { v4=v3;i4=i3; v3=v2;i3=i2; v2=v;i2=j; }
                    else if (v > v3) { v4=v3;i4=i3; v3=v;i3=j; }
                    else if (v > v4) { v4=v;i4=j; }
                }
            }
            keep = (cand >= TOPK_);
            if (keep) tops = (1ull<<i0)|(1ull<<i1)|(1ull<<i2)|(1ull<<i3)|(1ull<<i4);
            keep_s[tid] = keep ? 1 : 0; tops_s[tid] = tops;
        }
        __syncthreads();
        unsigned long long Mrow = 0ull;
        if (tid < m && keep) {
            for (int j = 0; j < 64; ++j) {
                if (j == tid || !keep_s[j]) continue;
                if (((tops >> j) & 1ull) || ((tops_s[j] >> tid) & 1ull)) Mrow |= (1ull << j);
            }
        }
        if (tid < 64) {
            unsigned long long b = __ballot(Mrow != 0ull);
            if (tid == 0) insub_sh = b;
        }
        __syncthreads();
    }
    unsigned long long sub = insub_sh;

    // ---------- decide on layer l ----------
    if (l != 7) {
        const float* Gc = G + ((size_t)l * NLAB + c) * GSTRIDE;
        load_tile(Gc, m, tid, Gs, rinv);
    }
    if (tid < 64) { keep_s[tid] = 0; tops_s[tid] = 0ull; }
    __syncthreads();
    unsigned long long tops = 0ull; bool keep = false; bool act = false;
    float emaval = 0.0f;
    if (tid < m) {
        act = (sub >> tid) & 1ull;
        if (act) {
            float v0=-1.f,v1=-1.f,v2=-1.f,v3=-1.f,v4=-1.f;
            int i0=0,i1=0,i2=0,i3=0,i4=0, cand=0, dg=0;
            float rs = 0.0f;
            #pragma unroll 8
            for (int j = 0; j < 64; ++j) {
                float v = Gs[tid][j];
                if (!((sub >> j) & 1ull)) v = -2.0f;
                if (v > 0.0f) {
                    rs += v; ++dg;                  // includes j == tid (diag ~ 1.0)
                    if (j != tid) {
                        ++cand;
                        if      (v > v0) { v4=v3;i4=i3; v3=v2;i3=i2; v2=v1;i2=i1; v1=v0;i1=i0; v0=v;i0=j; }
                        else if (v > v1) { v4=v3;i4=i3; v3=v2;i3=i2; v2=v1;i2=i1; v1=v;i1=j; }
                        else if (v > v2) { v4=v3;i4=i3; v3=v2;i3=i2; v2=v;i2=j; }
                        else if (v > v3) { v4=v3;i4=i3; v3=v;i3=j; }
                        else if (v > v4) { v4=v;i4=j; }
                    }
                }
            }
            keep = (cand >= TOPK_);
            if (keep) tops = (1ull<<i0)|(1ull<<i1)|(1ull<<i2)|(1ull<<i3)|(1ull<<i4);
            float deg = (float)(dg > 0 ? dg : 1);
            float score = 1.0f / (1.0f + expf(-rs / deg));
            emaval = 0.45f + 0.1f * score;          // MOM*0.5 + (1-MOM)*score
        }
        keep_s[tid] = keep ? 1 : 0; tops_s[tid] = tops;
    }
    __syncthreads();
    if (tid < m) {
        unsigned long long Mrow = 0ull;
        if (keep) {
            for (int j = 0; j < 64; ++j) {
                if (j == tid || !keep_s[j]) continue;
                if (((tops >> j) & 1ull) || ((tops_s[j] >> tid) & 1ull)) Mrow |= (1ull << j);
            }
        }
        Mbits[((size_t)l * NLAB + c) * MAXM + tid] = Mrow;
        ema[((size_t)l * NLAB + c) * MAXM + tid] = emaval;
    }
}

// ---------------------------------------------------------------------------
// Per (label, pair p): masked reduce -> private partial slot; ticket-fused
// final reduction (last of 896 blocks writes out).
// ---------------------------------------------------------------------------
__global__ __launch_bounds__(NTH) void k_pairs(
    const float* __restrict__ G, const int* __restrict__ cnt,
    const unsigned long long* __restrict__ Mbits, const float* __restrict__ ema,
    float* __restrict__ partial,   // [NL-1][NLAB][4]
    unsigned* __restrict__ ticket, float* __restrict__ out)
{
    __shared__ float r0[64], r1[64];
    __shared__ unsigned long long M0s[64], M1s[64];
    __shared__ float es[64];
    __shared__ float red[12];      // 4 waves x 3
    __shared__ unsigned done_s;
    int c = blockIdx.x, p = blockIdx.y, tid = threadIdx.x;
    int m = cnt[c]; if (m > MAXM) m = MAXM;
    const float* G0 = G + ((size_t)p       * NLAB + c) * GSTRIDE;
    const float* G1 = G + ((size_t)(p + 1) * NLAB + c) * GSTRIDE;
    if (tid < m) {
        M0s[tid] = Mbits[((size_t)p * NLAB + c) * MAXM + tid];
        M1s[tid] = Mbits[((size_t)(p + 1) * NLAB + c) * MAXM + tid];
        es[tid]  = ema[((size_t)p * NLAB + c) * MAXM + tid];   // W from shallow layer p
        r0[tid]  = 1.0f / fmaxf(sqrtf(G0[tid * MAXM + tid]), 1e-8f);
        r1[tid]  = 1.0f / fmaxf(sqrtf(G1[tid * MAXM + tid]), 1e-8f);
    }
    __syncthreads();
    float fn = 0.0f, fd = 0.0f, fc = 0.0f;
    for (int idx = tid; idx < (m << 6); idx += NTH) {
        int i = idx >> 6, j = idx & 63;
        if (j >= m) continue;
        bool b0 = (M0s[i] >> j) & 1ull;
        bool b1 = (M1s[i] >> j) & 1ull;
        if (b0 | b1) {
            float v0 = b0 ? fminf(fmaxf(G0[idx] * r0[i] * r0[j], -1.0f), 1.0f) : 0.0f;
            float v1 = b1 ? fminf(fmaxf(G1[idx] * r1[i] * r1[j], -1.0f), 1.0f) : 0.0f;
            float w = es[i] * es[j];
            float d = v1 - v0;
            fn = fmaf(d * d, w, fn);
            fd += w;
            fc += 1.0f;
        }
    }
    for (int off = 32; off > 0; off >>= 1) {
        fn += __shfl_down(fn, off);
        fd += __shfl_down(fd, off);
        fc += __shfl_down(fc, off);
    }
    int w = tid >> 6;
    if ((tid & 63) == 0) { red[w * 3] = fn; red[w * 3 + 1] = fd; red[w * 3 + 2] = fc; }
    __syncthreads();
    if (tid == 0) {
        float* dst = partial + ((size_t)p * NLAB + c) * 4;
        dst[0] = red[0] + red[3] + red[6] + red[9];
        dst[1] = red[1] + red[4] + red[7] + red[10];
        dst[2] = red[2] + red[5] + red[8] + red[11];
    }

    // ---------- ticket: last block does the final reduction ----------
    __threadfence();                    // make this block's partials visible
    __syncthreads();
    if (tid == 0) done_s = atomicAdd(ticket, 1u);
    __syncthreads();
    if (done_s == NLAB * (NL - 1) - 1) {
        __threadfence();                // see all other blocks' partials
        if (tid < 64) {
            float total = 0.0f;
            for (int pp = 0; pp < NL - 1; ++pp) {
                float nn = 0.0f, dd = 0.0f, cc = 0.0f;
                for (int ci = tid; ci < NLAB; ci += 64) {
                    const float* src = partial + ((size_t)pp * NLAB + ci) * 4;
                    nn += src[0]; dd += src[1]; cc += src[2];
                }
                for (int off = 32; off > 0; off >>= 1) {
                    nn += __shfl_down(nn, off);
                    dd += __shfl_down(dd, off);
                    cc += __shfl_down(cc, off);
                }
                if (tid == 0 && cc > 0.0f) total += nn / fmaxf(dd, 1e-8f);
            }
            if (tid == 0) out[0] = 16.0f * total / 7.0f;  // LAMBDA * sum / (L-1)
        }
    }
}

extern "C" void kernel_launch(void* const* d_in, const int* in_sizes, int n_in,
                              void* d_out, int out_size, void* d_ws, size_t ws_size,
                              hipStream_t stream) {
    const float* feats  = (const float*)d_in[0];
    const int*   labels = (const int*)d_in[1];
    // (sample_ids unused by the reference)
    char* w = (char*)d_ws;
    size_t gbytes = (size_t)NL * NLAB * GSTRIDE * 4;                 // 16,777,216
    float*    G       = (float*)(w);
    float*    partial = (float*)(w + gbytes);                        // 14,336 B
    unsigned* ticket  = (unsigned*)(w + gbytes + 14336);
    int*      cnt     = (int*)(w + gbytes + 14336 + 256);            // 512 B
    unsigned long long* Mbits = (unsigned long long*)(w + gbytes + 16384);   // 524,288
    float*    ema     = (float*)(w + gbytes + 16384 + 524288);       // 262,144
    float*    out     = (float*)d_out;

    k_gram  <<<dim3(NLAB, NL), NTH, 0, stream>>>(feats, labels, G, cnt, ticket);
    k_decide<<<dim3(NLAB, NL), NTH, 0, stream>>>(G, cnt, Mbits, ema);
    k_pairs <<<dim3(NLAB, NL - 1), NTH, 0, stream>>>(G, cnt, Mbits, ema, partial, ticket, out);
}

// Round 6
// 135.478 us; speedup vs baseline: 2.2375x; 1.3536x over previous
//
#include <hip/hip_runtime.h>
#include <cmath>

#define NB   2048
#define ND   512
#define NL   8
#define NLAB 128
#define MAXM 64
#define TOPK_ 5
#define NTH  256
#define MAXSLOT 9            // ceil(64*65/2 / 256)
#define GSTRIDE (MAXM*MAXM)  // 4096 floats per (label,layer) gram

// ---------------------------------------------------------------------------
// Fused bucket + raw Gram per (label, layer). Each block rebuilds its label's
// member list (index-ascending) from labels[] (8 KB, L2), computes the
// un-normalized dot Gram incl. diag. l==0 blocks publish cnt[c].
// ---------------------------------------------------------------------------
__global__ __launch_bounds__(NTH) void k_gram(
    const float* __restrict__ feats, const int* __restrict__ labels,
    float* __restrict__ G, int* __restrict__ cnt)
{
    __shared__ int cnts[NTH];
    __shared__ int g_s[MAXM];
    __shared__ float Xt[MAXM][132];   // 132%4==0 -> aligned float4 rows
    int c = blockIdx.x, l = blockIdx.y, tid = threadIdx.x;

    // in-block bucket (deterministic, index-ascending)
    int my[8]; int n = 0; int base_i = tid * 8;
    for (int t = 0; t < 8; ++t) {
        int i = base_i + t;
        if (labels[i] == c) my[n++] = i;
    }
    cnts[tid] = n;
    __syncthreads();
    for (int off = 1; off < NTH; off <<= 1) {
        int v = (tid >= off) ? cnts[tid - off] : 0;
        __syncthreads();
        cnts[tid] += v;
        __syncthreads();
    }
    int excl = cnts[tid] - n;
    int m = cnts[NTH - 1]; if (m > MAXM) m = MAXM;
    for (int t = 0; t < n; ++t) {
        int slot = excl + t;
        if (slot < MAXM) g_s[slot] = my[t];
    }
    if (l == 0 && tid == 0) cnt[c] = m;
    __syncthreads();
    if (m == 0) return;

    const float* X = feats + (size_t)l * NB * ND;
    const int P = m * (m + 1) / 2;    // triangular incl. diag
    float acc0[MAXSLOT], acc1[MAXSLOT];
    short is_[MAXSLOT], js_[MAXSLOT];
    int ns = 0;
    for (int p = tid; p < P; p += NTH) {
        int i = (int)((sqrtf(8.0f * (float)p + 1.0f) - 1.0f) * 0.5f);
        while (((i + 1) * (i + 2)) / 2 <= p) ++i;
        while ((i * (i + 1)) / 2 > p) --i;
        is_[ns] = (short)i;
        js_[ns] = (short)(p - (i * (i + 1)) / 2);
        acc0[ns] = 0.0f; acc1[ns] = 0.0f;
        ++ns;
    }
    for (int kc = 0; kc < ND; kc += 128) {
        if (kc) __syncthreads();      // previous chunk's readers done
        for (int idx = tid; idx < (m << 5); idx += NTH) {
            int i = idx >> 5, k4 = idx & 31;
            float4 v = *(const float4*)(X + ((size_t)g_s[i] << 9) + kc + (k4 << 2));
            *(float4*)&Xt[i][k4 << 2] = v;
        }
        __syncthreads();
        for (int s = 0; s < ns; ++s) {
            int i = is_[s], j = js_[s];
            float a0 = acc0[s], a1 = acc1[s];
            #pragma unroll
            for (int k4 = 0; k4 < 32; ++k4) {
                float4 a = *(const float4*)&Xt[i][k4 << 2];
                float4 b = *(const float4*)&Xt[j][k4 << 2];
                a0 = fmaf(a.x, b.x, a0); a1 = fmaf(a.y, b.y, a1);
                a0 = fmaf(a.z, b.z, a0); a1 = fmaf(a.w, b.w, a1);
            }
            acc0[s] = a0; acc1[s] = a1;
        }
    }
    float* Gc = G + ((size_t)l * NLAB + c) * GSTRIDE;
    for (int s = 0; s < ns; ++s) {
        int i = is_[s], j = js_[s];
        float v = acc0[s] + acc1[s];
        Gc[i * MAXM + j] = v;
        Gc[j * MAXM + i] = v;
    }
}

// Load normalized+clipped tile (full 64x64, sentinel -2.0f outside m x m).
__device__ __forceinline__ void load_tile(
    const float* __restrict__ Gc, int m, int tid, float (*Gs)[65], float* rinv)
{
    if (tid < 64) rinv[tid] = (tid < m) ? 1.0f / fmaxf(sqrtf(Gc[tid * MAXM + tid]), 1e-8f) : 0.0f;
    __syncthreads();
    for (int idx = tid; idx < 4096; idx += NTH) {
        int i = idx >> 6, j = idx & 63;
        float raw = Gc[idx];                       // may be poison outside m x m
        float v = fminf(fmaxf(raw * rinv[i] * rinv[j], -1.0f), 1.0f);
        Gs[i][j] = (i < m && j < m) ? v : -2.0f;   // sentinel: fails every >0 test
    }
    __syncthreads();
}

// ---------------------------------------------------------------------------
// Phase 1 (one block per label): layer-7 full-group knn -> insub bitmask.
// Top-k = single-pass 5-reg insertion (ascending j, strict > => ties->lowest
// index: identical selection to the verified iterative-max code).
// ---------------------------------------------------------------------------
__global__ __launch_bounds__(NTH) void k_phase1(
    const float* __restrict__ G, const int* __restrict__ cnt,
    unsigned long long* __restrict__ insub)
{
    __shared__ float Gs[64][65];
    __shared__ float rinv[64];
    __shared__ unsigned long long tops_s[64];
    __shared__ unsigned char keep_s[64];
    int c = blockIdx.x, tid = threadIdx.x;
    int m = cnt[c]; if (m > MAXM) m = MAXM;
    if (m == 0) { if (tid == 0) insub[c] = 0ull; return; }

    const float* Gc7 = G + ((size_t)7 * NLAB + c) * GSTRIDE;
    load_tile(Gc7, m, tid, Gs, rinv);
    if (tid < 64) { keep_s[tid] = 0; tops_s[tid] = 0ull; }
    __syncthreads();
    unsigned long long tops = 0ull; bool keep = false;
    if (tid < m) {
        float v0=-1.f,v1=-1.f,v2=-1.f,v3=-1.f,v4=-1.f;
        int i0=0,i1=0,i2=0,i3=0,i4=0, cand=0;
        #pragma unroll 8
        for (int j = 0; j < 64; ++j) {
            float v = Gs[tid][j];
            if (v > 0.0f && j != tid) {
                ++cand;
                if      (v > v0) { v4=v3;i4=i3; v3=v2;i3=i2; v2=v1;i2=i1; v1=v0;i1=i0; v0=v;i0=j; }
                else if (v > v1) { v4=v3;i4=i3; v3=v2;i3=i2; v2=v1;i2=i1; v1=v;i1=j; }
                else if (v > v2) { v4=v3;i4=i3; v3=v2;i3=i2; v2=v;i2=j; }
                else if (v > v3) { v4=v3;i4=i3; v3=v;i3=j; }
                else if (v > v4) { v4=v;i4=j; }
            }
        }
        keep = (cand >= TOPK_);
        if (keep) tops = (1ull<<i0)|(1ull<<i1)|(1ull<<i2)|(1ull<<i3)|(1ull<<i4);
        keep_s[tid] = keep ? 1 : 0; tops_s[tid] = tops;
    }
    __syncthreads();
    unsigned long long Mrow = 0ull;
    if (tid < m && keep) {
        for (int j = 0; j < 64; ++j) {
            if (j == tid || !keep_s[j]) continue;
            if (((tops >> j) & 1ull) || ((tops_s[j] >> tid) & 1ull)) Mrow |= (1ull << j);
        }
    }
    if (tid < 64) {
        unsigned long long b = __ballot(Mrow != 0ull);
        if (tid == 0) insub[c] = b;
    }
}

// ---------------------------------------------------------------------------
// Per (label, layer): subset-restricted knn -> Mbits + ema (insertion top-k).
// ---------------------------------------------------------------------------
__global__ __launch_bounds__(NTH) void k_decide(
    const float* __restrict__ G, const int* __restrict__ cnt,
    const unsigned long long* __restrict__ insub,
    unsigned long long* __restrict__ Mbits, float* __restrict__ ema)
{
    __shared__ float Gs[64][65];
    __shared__ float rinv[64];
    __shared__ unsigned long long tops_s[64];
    __shared__ unsigned char keep_s[64];
    int c = blockIdx.x, l = blockIdx.y, tid = threadIdx.x;
    int m = cnt[c]; if (m > MAXM) m = MAXM;
    if (m == 0) return;
    unsigned long long sub = insub[c];

    const float* Gc = G + ((size_t)l * NLAB + c) * GSTRIDE;
    load_tile(Gc, m, tid, Gs, rinv);
    if (tid < 64) { keep_s[tid] = 0; tops_s[tid] = 0ull; }
    __syncthreads();
    unsigned long long tops = 0ull; bool keep = false; bool act = false;
    float emaval = 0.0f;
    if (tid < m) {
        act = (sub >> tid) & 1ull;
        if (act) {
            float v0=-1.f,v1=-1.f,v2=-1.f,v3=-1.f,v4=-1.f;
            int i0=0,i1=0,i2=0,i3=0,i4=0, cand=0, dg=0;
            float rs = 0.0f;
            #pragma unroll 8
            for (int j = 0; j < 64; ++j) {
                float v = Gs[tid][j];
                if (!((sub >> j) & 1ull)) v = -2.0f;
                if (v > 0.0f) {
                    rs += v; ++dg;                  // includes j == tid (diag ~ 1.0)
                    if (j != tid) {
                        ++cand;
                        if      (v > v0) { v4=v3;i4=i3; v3=v2;i3=i2; v2=v1;i2=i1; v1=v0;i1=i0; v0=v;i0=j; }
                        else if (v > v1) { v4=v3;i4=i3; v3=v2;i3=i2; v2=v1;i2=i1; v1=v;i1=j; }
                        else if (v > v2) { v4=v3;i4=i3; v3=v2;i3=i2; v2=v;i2=j; }
                        else if (v > v3) { v4=v3;i4=i3; v3=v;i3=j; }
                        else if (v > v4) { v4=v;i4=j; }
                    }
                }
            }
            keep = (cand >= TOPK_);
            if (keep) tops = (1ull<<i0)|(1ull<<i1)|(1ull<<i2)|(1ull<<i3)|(1ull<<i4);
            float deg = (float)(dg > 0 ? dg : 1);
            float score = 1.0f / (1.0f + expf(-rs / deg));
            emaval = 0.45f + 0.1f * score;          // MOM*0.5 + (1-MOM)*score
        }
        keep_s[tid] = keep ? 1 : 0; tops_s[tid] = tops;
    }
    __syncthreads();
    if (tid < m) {
        unsigned long long Mrow = 0ull;
        if (keep) {
            for (int j = 0; j < 64; ++j) {
                if (j == tid || !keep_s[j]) continue;
                if (((tops >> j) & 1ull) || ((tops_s[j] >> tid) & 1ull)) Mrow |= (1ull << j);
            }
        }
        Mbits[((size_t)l * NLAB + c) * MAXM + tid] = Mrow;
        ema[((size_t)l * NLAB + c) * MAXM + tid] = emaval;
    }
}

// ---------------------------------------------------------------------------
// Per (label, pair p): masked reduce -> private partial slot. No atomics,
// no fences (round-5 post-mortem: threadfence+ticket cost 63us in L2 thrash).
// ---------------------------------------------------------------------------
__global__ __launch_bounds__(NTH) void k_pairs(
    const float* __restrict__ G, const int* __restrict__ cnt,
    const unsigned long long* __restrict__ Mbits, const float* __restrict__ ema,
    float* __restrict__ partial)   // [NL-1][NLAB][4]
{
    __shared__ float r0[64], r1[64];
    __shared__ unsigned long long M0s[64], M1s[64];
    __shared__ float es[64];
    __shared__ float red[12];      // 4 waves x 3
    int c = blockIdx.x, p = blockIdx.y, tid = threadIdx.x;
    int m = cnt[c]; if (m > MAXM) m = MAXM;
    const float* G0 = G + ((size_t)p       * NLAB + c) * GSTRIDE;
    const float* G1 = G + ((size_t)(p + 1) * NLAB + c) * GSTRIDE;
    if (tid < m) {
        M0s[tid] = Mbits[((size_t)p * NLAB + c) * MAXM + tid];
        M1s[tid] = Mbits[((size_t)(p + 1) * NLAB + c) * MAXM + tid];
        es[tid]  = ema[((size_t)p * NLAB + c) * MAXM + tid];   // W from shallow layer p
        r0[tid]  = 1.0f / fmaxf(sqrtf(G0[tid * MAXM + tid]), 1e-8f);
        r1[tid]  = 1.0f / fmaxf(sqrtf(G1[tid * MAXM + tid]), 1e-8f);
    }
    __syncthreads();
    float fn = 0.0f, fd = 0.0f, fc = 0.0f;
    for (int idx = tid; idx < (m << 6); idx += NTH) {
        int i = idx >> 6, j = idx & 63;
        if (j >= m) continue;
        bool b0 = (M0s[i] >> j) & 1ull;
        bool b1 = (M1s[i] >> j) & 1ull;
        if (b0 | b1) {
            float v0 = b0 ? fminf(fmaxf(G0[idx] * r0[i] * r0[j], -1.0f), 1.0f) : 0.0f;
            float v1 = b1 ? fminf(fmaxf(G1[idx] * r1[i] * r1[j], -1.0f), 1.0f) : 0.0f;
            float w = es[i] * es[j];
            float d = v1 - v0;
            fn = fmaf(d * d, w, fn);
            fd += w;
            fc += 1.0f;
        }
    }
    for (int off = 32; off > 0; off >>= 1) {
        fn += __shfl_down(fn, off);
        fd += __shfl_down(fd, off);
        fc += __shfl_down(fc, off);
    }
    int w = tid >> 6;
    if ((tid & 63) == 0) { red[w * 3] = fn; red[w * 3 + 1] = fd; red[w * 3 + 2] = fc; }
    __syncthreads();
    if (tid == 0) {
        float* dst = partial + ((size_t)p * NLAB + c) * 4;
        dst[0] = red[0] + red[3] + red[6] + red[9];
        dst[1] = red[1] + red[4] + red[7] + red[10];
        dst[2] = red[2] + red[5] + red[8] + red[11];
    }
}

// Single-wave final reduction over 896 private slots (~14 KB, L2-hit).
__global__ void k_final(const float* __restrict__ partial, float* __restrict__ out)
{
    int tid = threadIdx.x;
    float total = 0.0f;
    for (int p = 0; p < NL - 1; ++p) {
        float n = 0.0f, d = 0.0f, cc = 0.0f;
        for (int c = tid; c < NLAB; c += 64) {
            const float* src = partial + ((size_t)p * NLAB + c) * 4;
            n += src[0]; d += src[1]; cc += src[2];
        }
        for (int off = 32; off > 0; off >>= 1) {
            n += __shfl_down(n, off);
            d += __shfl_down(d, off);
            cc += __shfl_down(cc, off);
        }
        if (tid == 0 && cc > 0.0f) total += n / fmaxf(d, 1e-8f);
    }
    if (tid == 0) out[0] = 16.0f * total / 7.0f;   // LAMBDA_ALIGN_K * sum / (L-1)
}

extern "C" void kernel_launch(void* const* d_in, const int* in_sizes, int n_in,
                              void* d_out, int out_size, void* d_ws, size_t ws_size,
                              hipStream_t stream) {
    const float* feats  = (const float*)d_in[0];
    const int*   labels = (const int*)d_in[1];
    // (sample_ids unused by the reference)
    char* w = (char*)d_ws;
    size_t gbytes = (size_t)NL * NLAB * GSTRIDE * 4;                 // 16,777,216
    float*    G       = (float*)(w);
    float*    partial = (float*)(w + gbytes);                        // 14,336 B
    int*      cnt     = (int*)(w + gbytes + 14336);                  // 512 B
    unsigned long long* insub = (unsigned long long*)(w + gbytes + 14848);   // 1,024 B
    unsigned long long* Mbits = (unsigned long long*)(w + gbytes + 16384);   // 524,288
    float*    ema     = (float*)(w + gbytes + 16384 + 524288);       // 262,144
    float*    out     = (float*)d_out;

    k_gram  <<<dim3(NLAB, NL), NTH, 0, stream>>>(feats, labels, G, cnt);
    k_phase1<<<NLAB, NTH, 0, stream>>>(G, cnt, insub);
    k_decide<<<dim3(NLAB, NL), NTH, 0, stream>>>(G, cnt, insub, Mbits, ema);
    k_pairs <<<dim3(NLAB, NL - 1), NTH, 0, stream>>>(G, cnt, Mbits, ema, partial);
    k_final <<<1, 64, 0, stream>>>(partial, out);
}